// Round 7
// baseline (157.204 us; speedup 1.0000x reference)
//
#include <hip/hip_runtime.h>
#include <hip/hip_bf16.h>

typedef __hip_bfloat16 bf16;
typedef unsigned short u16;
typedef unsigned int   u32;

#define B_    32
#define D_    512
#define HID_  256
#define NF_   8
#define CIN_  64
#define COUT_ 64
#define HW_   64
#define CONV_OUT_ELEMS (B_ * COUT_ * HW_ * HW_)   // 8388608
#define WBANK_ (NF_ * 36864)                       // weight elems

typedef __attribute__((ext_vector_type(8))) short  short8;   // 8 bf16 = 4 VGPRs (MFMA A/B frag)
typedef __attribute__((ext_vector_type(4))) float  floatx4;  // MFMA C/D frag

__device__ inline float b2f(bf16 v) { return __bfloat162float(v); }
__device__ inline bf16  f2b(float f) { return __float2bfloat16(f); }
__device__ inline u16 f2bu(float f) { union { bf16 h; u16 u; } c; c.h = __float2bfloat16(f); return c.u; }
__device__ inline float bu2f(u16 u) { union { u32 i; float f; } c; c.i = ((u32)u) << 16; return c.f; }

__device__ inline float ldf(const void* p, int i, int isbf) {
    return isbf ? __bfloat162float(((const bf16*)p)[i]) : ((const float*)p)[i];
}

// word is "bf16-sane" if low 16 bits decode to zero or normal-exponent bf16
__device__ inline int word_bf16_sane(u32 v) {
    u32 lo = v & 0xFFFFu;
    u32 ex = (lo >> 7) & 0xFFu;
    return (lo == 0u || (ex >= 64u && ex <= 191u)) ? 1 : 0;
}

// ---------------------------------------------------------------------------
// Kernel 1: prep = xin transpose (blocks 0..2047) + fc1 (blocks 2048..2303).
// Transpose: NCHW (fp32 or bf16) -> NHWC bf16 xin_t[b][y][x][ci], per-block
// one (b,y) row: coalesced reads, LDS transpose, coalesced uint4 writes.
// fc1: one hidden unit per block; thread (b,seg) covers 64 k-elems, all loads
// up-front, 3-step shfl reduce.
// ---------------------------------------------------------------------------
__global__ __launch_bounds__(256) void prep_kernel(
    const void* __restrict__ xin,    // [32][64][64][64] NCHW
    const void* __restrict__ x,      // [32,512]
    const void* __restrict__ fc1_w,  // [256,512]
    const void* __restrict__ fc1_b,  // [256]
    u16* __restrict__ xin_t,         // [32][64][64][64] NHWC bf16
    float* __restrict__ ws_hs)       // [32,256]
{
    __shared__ u16 tr[64][66];
    __shared__ int fl[4];
    const int blk = blockIdx.x;
    const int t = threadIdx.x;

    if (blk < 2048) {
        // ---------------- transpose one (b, y) row ----------------
        const int b = blk >> 6, y = blk & 63;
        if (t == 0) fl[0] = 1;
        __syncthreads();
        if (t < 32) {
            u32 w = ((const u32*)xin)[t * 131072];
            if (!word_bf16_sane(w)) atomicAnd(&fl[0], 0);
        }
        __syncthreads();
        const int inbf = fl[0];

        const int ci = t >> 2, xq = (t & 3) * 16;
        u16 vals[16];
        if (inbf) {
            const bf16* src = (const bf16*)xin + (((b * CIN_ + ci) * HW_ + y) * HW_ + xq);
            uint4 v0 = *(const uint4*)src;
            uint4 v1 = *(const uint4*)(src + 8);
            const u32 w8[8] = { v0.x, v0.y, v0.z, v0.w, v1.x, v1.y, v1.z, v1.w };
#pragma unroll
            for (int k = 0; k < 8; ++k) {
                vals[2 * k]     = (u16)(w8[k] & 0xFFFF);
                vals[2 * k + 1] = (u16)(w8[k] >> 16);
            }
        } else {
            const float* src = (const float*)xin + (((b * CIN_ + ci) * HW_ + y) * HW_ + xq);
#pragma unroll
            for (int c = 0; c < 4; ++c) {
                float4 f = *(const float4*)(src + c * 4);
                vals[c * 4 + 0] = f2bu(f.x); vals[c * 4 + 1] = f2bu(f.y);
                vals[c * 4 + 2] = f2bu(f.z); vals[c * 4 + 3] = f2bu(f.w);
            }
        }
#pragma unroll
        for (int k = 0; k < 16; ++k) tr[xq + k][ci] = vals[k];
        __syncthreads();

        const int px = t >> 2, cg = (t & 3) * 16;
        u32 wd[8];
#pragma unroll
        for (int w = 0; w < 8; ++w)
            wd[w] = (u32)tr[px][cg + 2 * w] | ((u32)tr[px][cg + 2 * w + 1] << 16);
        u16* dst = xin_t + (((b * HW_ + y) * HW_ + px) * CIN_ + cg);
        ((uint4*)dst)[0] = make_uint4(wd[0], wd[1], wd[2], wd[3]);
        ((uint4*)dst)[1] = make_uint4(wd[4], wd[5], wd[6], wd[7]);
        return;
    }

    // ---------------- fc1: hidden unit h ----------------
    const int h = blk - 2048;
    const int b = t >> 3, seg = t & 7;
    if (t < 3) fl[t] = 1;
    __syncthreads();
    if (t < 96) {
        const int g = t >> 5, k = t & 31;
        const void* buf = (g == 0) ? x : (g == 1) ? fc1_w : fc1_b;
        const int elems = (g == 0) ? B_ * D_ : (g == 1) ? HID_ * D_ : HID_;
        const int nw = elems >> 1;
        const int n = nw < 32 ? nw : 32;
        if (k < n && nw >= 1) {
            u32 v = ((const u32*)buf)[k * (nw / n)];
            if (!word_bf16_sane(v)) atomicAnd(&fl[g], 0);
        }
    }
    __syncthreads();
    const int xbf = fl[0], wbf = fl[1], b1bf = fl[2];

    const int xoff = b * D_ + seg * 64;
    const int woff = h * D_ + seg * 64;
    float p = 0.f;
    if (!xbf && !wbf) {
        float4 xr[16], wr[16];                      // 16 x float4 = 64 floats
        const float4* xp = (const float4*)((const float*)x + xoff);
        const float4* wp = (const float4*)((const float*)fc1_w + woff);
#pragma unroll
        for (int c = 0; c < 16; ++c) xr[c] = xp[c];
#pragma unroll
        for (int c = 0; c < 16; ++c) wr[c] = wp[c];
#pragma unroll
        for (int c = 0; c < 16; ++c)
            p += xr[c].x * wr[c].x + xr[c].y * wr[c].y + xr[c].z * wr[c].z + xr[c].w * wr[c].w;
    } else if (xbf && wbf) {
        uint4 xr[8], wr[8];                         // 8 x uint4 = 64 bf16
        const uint4* xp = (const uint4*)((const bf16*)x + xoff);
        const uint4* wp = (const uint4*)((const bf16*)fc1_w + woff);
#pragma unroll
        for (int c = 0; c < 8; ++c) xr[c] = xp[c];
#pragma unroll
        for (int c = 0; c < 8; ++c) wr[c] = wp[c];
#pragma unroll
        for (int c = 0; c < 8; ++c) {
            const u32 xw[4] = { xr[c].x, xr[c].y, xr[c].z, xr[c].w };
            const u32 ww[4] = { wr[c].x, wr[c].y, wr[c].z, wr[c].w };
#pragma unroll
            for (int q2 = 0; q2 < 4; ++q2)
                p += bu2f((u16)(xw[q2] & 0xFFFF)) * bu2f((u16)(ww[q2] & 0xFFFF))
                   + bu2f((u16)(xw[q2] >> 16))    * bu2f((u16)(ww[q2] >> 16));
        }
    } else {
        for (int c = 0; c < 64; ++c) p += ldf(x, xoff + c, xbf) * ldf(fc1_w, woff + c, wbf);
    }
    p += __shfl_xor(p, 1);
    p += __shfl_xor(p, 2);
    p += __shfl_xor(p, 4);
    if (seg == 0) {
        p += ldf(fc1_b, h, b1bf);
        ws_hs[b * HID_ + h] = p > 0.f ? p : 0.f;
    }
}

// ---------------------------------------------------------------------------
// Kernel 2: fc2 + softmax + attn outputs + aggregated bias.  grid = 32.
// ---------------------------------------------------------------------------
__global__ __launch_bounds__(256) void fc2_kernel(
    const void* __restrict__ fc2_w,  // [8,256]
    const void* __restrict__ fc2_b,  // [8]
    const void* __restrict__ bias_p, // [8,64]
    const void* __restrict__ xin,    // output-dtype proxy
    const float* __restrict__ ws_hs, // [32,256]
    float* __restrict__ ws_attn, float* __restrict__ ws_aggb,
    void* __restrict__ d_out)
{
    __shared__ float hs[HID_];
    __shared__ float at[NF_];
    __shared__ int fl[4];
    const int b = blockIdx.x, t = threadIdx.x;
    if (t < 4) fl[t] = 1;
    hs[t] = ws_hs[b * HID_ + t];
    __syncthreads();
    if (t < 128) {
        const int g = t >> 5, k = t & 31;
        const void* buf = (g == 0) ? fc2_w : (g == 1) ? fc2_b : (g == 2) ? bias_p : xin;
        const int elems = (g == 0) ? NF_ * HID_ : (g == 1) ? NF_ : (g == 2) ? NF_ * COUT_
                                                : B_ * CIN_ * HW_ * HW_;
        const int nw = elems >> 1;
        const int n = nw < 32 ? nw : 32;
        if (k < n && nw >= 1) {
            u32 v = ((const u32*)buf)[k * (nw / n)];
            if (!word_bf16_sane(v)) atomicAnd(&fl[g], 0);
        }
    }
    __syncthreads();
    const int w2bf = fl[0], b2bf = fl[1], bpbf = fl[2], obf = fl[3];

    const int f = t >> 5, j = t & 31;
    const float* hp = hs + j * 8;
    float p;
    if (w2bf) {
        uint4 u = *(const uint4*)((const bf16*)fc2_w + f * HID_ + j * 8);
        p = bu2f((u16)(u.x & 0xFFFF)) * hp[0] + bu2f((u16)(u.x >> 16)) * hp[1]
          + bu2f((u16)(u.y & 0xFFFF)) * hp[2] + bu2f((u16)(u.y >> 16)) * hp[3]
          + bu2f((u16)(u.z & 0xFFFF)) * hp[4] + bu2f((u16)(u.z >> 16)) * hp[5]
          + bu2f((u16)(u.w & 0xFFFF)) * hp[6] + bu2f((u16)(u.w >> 16)) * hp[7];
    } else {
        const float* r = (const float*)fc2_w + f * HID_ + j * 8;
        float4 a = *(const float4*)r, c = *(const float4*)(r + 4);
        p = a.x * hp[0] + a.y * hp[1] + a.z * hp[2] + a.w * hp[3]
          + c.x * hp[4] + c.y * hp[5] + c.z * hp[6] + c.w * hp[7];
    }
#pragma unroll
    for (int m = 16; m; m >>= 1) p += __shfl_xor(p, m);
    if (j == 0) at[f] = (p + ldf(fc2_b, f, b2bf)) * (1.0f / 30.0f);
    __syncthreads();

    if (t == 0) {
        float m = at[0];
#pragma unroll
        for (int ff = 1; ff < NF_; ++ff) m = fmaxf(m, at[ff]);
        float e[NF_], ssum = 0.f;
#pragma unroll
        for (int ff = 0; ff < NF_; ++ff) { e[ff] = __expf(at[ff] - m); ssum += e[ff]; }
        float inv = 1.0f / ssum;
#pragma unroll
        for (int ff = 0; ff < NF_; ++ff) at[ff] = e[ff] * inv;
    }
    __syncthreads();
    if (t < NF_) {
        ws_attn[b * NF_ + t] = at[t];
        if (obf) ((bf16*)d_out)[CONV_OUT_ELEMS + b * NF_ + t] = f2b(at[t]);
        else    ((float*)d_out)[CONV_OUT_ELEMS + b * NF_ + t] = at[t];
    }
    if (t < COUT_) {
        float s = 0.f;
#pragma unroll
        for (int ff = 0; ff < NF_; ++ff) s += at[ff] * ldf(bias_p, ff * COUT_ + t, bpbf);
        ws_aggb[b * COUT_ + t] = s;
    }
}

// ---------------------------------------------------------------------------
// Kernel 3: aggregate kernel bank -> bf16 in MFMA layout [b][tap][o][ci].
// grid = 32 samples * 16 o-quads = 512 blocks, 256 threads.
// ---------------------------------------------------------------------------
__global__ __launch_bounds__(256) void agg_kernel(
    const void* __restrict__ weight,   // [8][64][64][3][3]
    const float* __restrict__ ws_attn, // [32][8]
    u16* __restrict__ aggw)            // [32][9][64][64] bf16
{
    __shared__ float lds[2304];        // [o_l(4)][ci(64)][tap(9)]
    __shared__ float s_at[NF_];
    __shared__ int   s_wbf;
    const int t  = threadIdx.x;
    const int b  = blockIdx.x >> 4;
    const int o0 = (blockIdx.x & 15) * 4;

    if (t == 0) s_wbf = 1;
    if (t < NF_) s_at[t] = ws_attn[b * NF_ + t];
    __syncthreads();
    if (t < 32) {
        const int nw = WBANK_ >> 1, step = nw / 32;
        u32 v = ((const u32*)weight)[t * step];
        if (!word_bf16_sane(v)) atomicAnd(&s_wbf, 0);
    }
    __syncthreads();
    const int wbf = s_wbf;

#pragma unroll
    for (int j = 0; j < 9; ++j) {
        const int flat = t + 256 * j;              // < 2304
        const int o_l = flat / 576, rr = flat - o_l * 576;  // rr = ci*9+tap
        const int gbase = (o0 + o_l) * 576 + rr;
        float s = 0.f;
        if (wbf) {
#pragma unroll
            for (int f = 0; f < NF_; ++f) s += s_at[f] * b2f(((const bf16*)weight)[f * 36864 + gbase]);
        } else {
#pragma unroll
            for (int f = 0; f < NF_; ++f) s += s_at[f] * ((const float*)weight)[f * 36864 + gbase];
        }
        lds[flat] = s;
    }
    __syncthreads();
#pragma unroll
    for (int j = 0; j < 9; ++j) {
        const int e = t + 256 * j;                 // tap(9) x o_l(4) x ci(64)
        const int tap = e >> 8, o_l = (e >> 6) & 3, ci = e & 63;
        aggw[b * 36864 + tap * 4096 + (o0 + o_l) * 64 + ci] = f2bu(lds[o_l * 576 + ci * 9 + tap]);
    }
}

// ---------------------------------------------------------------------------
// Kernel 4: barrier-free MFMA conv.  A and B frags loaded DIRECTLY from
// global (both 16B-contiguous: aggw[b][tap][o][ci], xin_t[b][y][x][ci]).
// Block = (sample, 4-row chunk); wave wv = output row y0+wv x 64 couts.
// No K-loop LDS, no K-loop barriers; LDS only for output coalescing.
// ---------------------------------------------------------------------------
__global__ __launch_bounds__(256) void conv_mfma2(
    const u16*  __restrict__ xin_t,   // [32][64][64][64] NHWC bf16
    const u16*  __restrict__ aggw,    // [32][9][64][64] bf16
    const float* __restrict__ aggb,   // [32][64]
    const void* __restrict__ xin,     // out-dtype proxy
    void* __restrict__ out)
{
    __shared__ u16 out_s[4 * 64 * 68];   // 34816 B
    __shared__ float bias_s[COUT_];
    __shared__ int s_ok;

    const int t    = threadIdx.x;
    const int bz   = blockIdx.x;
    const int b    = bz >> 4;
    const int y0   = (bz & 15) * 4;
    const int wv   = t >> 6;
    const int lane = t & 63, l15 = lane & 15, q = lane >> 4;

    if (t == 0) s_ok = 1;
    __syncthreads();
    if (t < 32) {
        u32 w = ((const u32*)xin)[t * 131072];
        if (!word_bf16_sane(w)) atomicAnd(&s_ok, 0);
    }
    if (t < COUT_) bias_s[t] = aggb[b * COUT_ + t];
    __syncthreads();
    const int outbf = s_ok;

    floatx4 acc[4][4];
#pragma unroll
    for (int mt = 0; mt < 4; ++mt)
#pragma unroll
        for (int nt = 0; nt < 4; ++nt) acc[mt][nt] = (floatx4)0.f;

    const u16* Abase = aggw + b * 36864;                 // [tap][o][ci]
    const int laneA = l15 * 64 + q * 8;                  // o=l15(+mt*16), ci=q*8(+ks*32)
    const int laneB = l15 * 64 + q * 8;                  // x=l15(+nt*16), ci=q*8(+ks*32)

#pragma unroll
    for (int kh = 0; kh < 3; ++kh) {
        const int gy = y0 + wv + kh - 1;
        if (gy >= 0 && gy < HW_) {                       // wave-uniform skip
            const u16* Brow = xin_t + (b * HW_ + gy) * (HW_ * CIN_);
#pragma unroll
            for (int kw = 0; kw < 3; ++kw) {
                const u16* Atap = Abase + (kh * 3 + kw) * 4096;
#pragma unroll
                for (int ks = 0; ks < 2; ++ks) {
                    short8 af[4], bf[4];
#pragma unroll
                    for (int mt = 0; mt < 4; ++mt)
                        af[mt] = *(const short8*)(Atap + mt * 1024 + ks * 32 + laneA);
#pragma unroll
                    for (int nt = 0; nt < 4; ++nt) {
                        const int col = nt * 16 + l15 + kw - 1;
                        if (col >= 0 && col < HW_)
                            bf[nt] = *(const short8*)(Brow + col * 64 + ks * 32 + q * 8);
                        else
                            bf[nt] = (short8)0;
                    }
#pragma unroll
                    for (int mt = 0; mt < 4; ++mt)
#pragma unroll
                        for (int nt = 0; nt < 4; ++nt)
                            acc[mt][nt] = __builtin_amdgcn_mfma_f32_16x16x32_bf16(
                                af[mt], bf[nt], acc[mt][nt], 0, 0, 0);
                }
            }
        }
    }

    // epilogue: + bias, stage in LDS for coalesced global write
#pragma unroll
    for (int mt = 0; mt < 4; ++mt) {
        floatx4 bb = *(const floatx4*)&bias_s[mt * 16 + q * 4];
#pragma unroll
        for (int nt = 0; nt < 4; ++nt) {
#pragma unroll
            for (int rg = 0; rg < 4; ++rg) {
                const float v = acc[mt][nt][rg] + bb[rg];
                out_s[(wv * 64 + (mt * 16 + q * 4 + rg)) * 68 + nt * 16 + l15] = f2bu(v);
            }
        }
    }
    __syncthreads();
#pragma unroll
    for (int j = 0; j < 16; ++j) {
        const int c = t + 256 * j;                 // 4096 chunks of 4 elems
        const int x0 = (c & 15) * 4, o = (c >> 4) & 63, w2 = c >> 10;
        const u16* src = &out_s[(w2 * 64 + o) * 68 + x0];
        const u16 h0 = src[0], h1 = src[1], h2 = src[2], h3 = src[3];
        const int gidx = ((b * COUT_ + o) * HW_ + (y0 + w2)) * HW_ + x0;
        if (outbf) {
            uint2 pk; pk.x = (u32)h0 | ((u32)h1 << 16); pk.y = (u32)h2 | ((u32)h3 << 16);
            *(uint2*)((u16*)out + gidx) = pk;
        } else {
            float4 f; f.x = bu2f(h0); f.y = bu2f(h1); f.z = bu2f(h2); f.w = bu2f(h3);
            *(float4*)((float*)out + gidx) = f;
        }
    }
}

// ---------------------------------------------------------------------------
extern "C" void kernel_launch(void* const* d_in, const int* in_sizes, int n_in,
                              void* d_out, int out_size, void* d_ws, size_t ws_size,
                              hipStream_t stream) {
    const void* x      = d_in[0];
    const void* xin    = d_in[1];
    const void* fc1_w  = d_in[2];
    const void* fc1_b  = d_in[3];
    const void* fc2_w  = d_in[4];
    const void* fc2_b  = d_in[5];
    const void* weight = d_in[6];
    const void* bias_p = d_in[7];

    float* ws      = (float*)d_ws;
    float* ws_attn = ws;                    // 256 floats
    float* ws_aggb = ws + 256;              // 2048 floats
    float* ws_hs   = ws + 2304;             // 8192 floats [32][256]
    u16*   ws_aggw = (u16*)(ws + 10496);    // 1,179,648 u16 (=589,824 float slots)
    u16*   ws_xint = (u16*)(ws + 600320);   // 8,388,608 u16 = 16.8 MB

    prep_kernel<<<dim3(2048 + HID_), dim3(256), 0, stream>>>(
        xin, x, fc1_w, fc1_b, ws_xint, ws_hs);

    fc2_kernel<<<dim3(B_), dim3(256), 0, stream>>>(
        fc2_w, fc2_b, bias_p, xin, ws_hs, ws_attn, ws_aggb, d_out);

    agg_kernel<<<dim3(B_ * 16), dim3(256), 0, stream>>>(weight, ws_attn, ws_aggw);

    conv_mfma2<<<dim3(B_ * 16), dim3(256), 0, stream>>>(
        ws_xint, ws_aggw, ws_aggb, xin, d_out);
}

// Round 8
// 147.226 us; speedup vs baseline: 1.0678x; 1.0678x over previous
//
#include <hip/hip_runtime.h>
#include <hip/hip_bf16.h>

typedef __hip_bfloat16 bf16;
typedef unsigned short u16;
typedef unsigned int   u32;

#define B_    32
#define D_    512
#define HID_  256
#define NF_   8
#define CIN_  64
#define COUT_ 64
#define HW_   64
#define CONV_OUT_ELEMS (B_ * COUT_ * HW_ * HW_)   // 8388608
#define WBANK_ (NF_ * 36864)                       // weight elems

typedef __attribute__((ext_vector_type(8))) short  short8;   // 8 bf16 = 4 VGPRs (MFMA A/B frag)
typedef __attribute__((ext_vector_type(4))) float  floatx4;  // MFMA C/D frag

__device__ inline float b2f(bf16 v) { return __bfloat162float(v); }
__device__ inline bf16  f2b(float f) { return __float2bfloat16(f); }
__device__ inline u16 f2bu(float f) { union { bf16 h; u16 u; } c; c.h = __float2bfloat16(f); return c.u; }
__device__ inline float bu2f(u16 u) { union { u32 i; float f; } c; c.i = ((u32)u) << 16; return c.f; }

__device__ inline float ldf(const void* p, int i, int isbf) {
    return isbf ? __bfloat162float(((const bf16*)p)[i]) : ((const float*)p)[i];
}

// word is "bf16-sane" if low 16 bits decode to zero or normal-exponent bf16
__device__ inline int word_bf16_sane(u32 v) {
    u32 lo = v & 0xFFFFu;
    u32 ex = (lo >> 7) & 0xFFu;
    return (lo == 0u || (ex >= 64u && ex <= 191u)) ? 1 : 0;
}

// ---------------------------------------------------------------------------
// Kernel 1: prep = xin transpose (blocks 0..2047) + fc1 (blocks 2048..2303).
// Transpose: NCHW (fp32 or bf16) -> NHWC bf16 xin_t[b][y][x][ci].
// ---------------------------------------------------------------------------
__global__ __launch_bounds__(256) void prep_kernel(
    const void* __restrict__ xin,    // [32][64][64][64] NCHW
    const void* __restrict__ x,      // [32,512]
    const void* __restrict__ fc1_w,  // [256,512]
    const void* __restrict__ fc1_b,  // [256]
    u16* __restrict__ xin_t,         // [32][64][64][64] NHWC bf16
    float* __restrict__ ws_hs)       // [32,256]
{
    __shared__ u16 tr[64][66];
    __shared__ int fl[4];
    const int blk = blockIdx.x;
    const int t = threadIdx.x;

    if (blk < 2048) {
        // ---------------- transpose one (b, y) row ----------------
        const int b = blk >> 6, y = blk & 63;
        if (t == 0) fl[0] = 1;
        __syncthreads();
        if (t < 32) {
            u32 w = ((const u32*)xin)[t * 131072];
            if (!word_bf16_sane(w)) atomicAnd(&fl[0], 0);
        }
        __syncthreads();
        const int inbf = fl[0];

        const int ci = t >> 2, xq = (t & 3) * 16;
        u16 vals[16];
        if (inbf) {
            const bf16* src = (const bf16*)xin + (((b * CIN_ + ci) * HW_ + y) * HW_ + xq);
            uint4 v0 = *(const uint4*)src;
            uint4 v1 = *(const uint4*)(src + 8);
            const u32 w8[8] = { v0.x, v0.y, v0.z, v0.w, v1.x, v1.y, v1.z, v1.w };
#pragma unroll
            for (int k = 0; k < 8; ++k) {
                vals[2 * k]     = (u16)(w8[k] & 0xFFFF);
                vals[2 * k + 1] = (u16)(w8[k] >> 16);
            }
        } else {
            const float* src = (const float*)xin + (((b * CIN_ + ci) * HW_ + y) * HW_ + xq);
#pragma unroll
            for (int c = 0; c < 4; ++c) {
                float4 f = *(const float4*)(src + c * 4);
                vals[c * 4 + 0] = f2bu(f.x); vals[c * 4 + 1] = f2bu(f.y);
                vals[c * 4 + 2] = f2bu(f.z); vals[c * 4 + 3] = f2bu(f.w);
            }
        }
#pragma unroll
        for (int k = 0; k < 16; ++k) tr[xq + k][ci] = vals[k];
        __syncthreads();

        const int px = t >> 2, cg = (t & 3) * 16;
        u32 wd[8];
#pragma unroll
        for (int w = 0; w < 8; ++w)
            wd[w] = (u32)tr[px][cg + 2 * w] | ((u32)tr[px][cg + 2 * w + 1] << 16);
        u16* dst = xin_t + (((b * HW_ + y) * HW_ + px) * CIN_ + cg);
        ((uint4*)dst)[0] = make_uint4(wd[0], wd[1], wd[2], wd[3]);
        ((uint4*)dst)[1] = make_uint4(wd[4], wd[5], wd[6], wd[7]);
        return;
    }

    // ---------------- fc1: hidden unit h ----------------
    const int h = blk - 2048;
    const int b = t >> 3, seg = t & 7;
    if (t < 3) fl[t] = 1;
    __syncthreads();
    if (t < 96) {
        const int g = t >> 5, k = t & 31;
        const void* buf = (g == 0) ? x : (g == 1) ? fc1_w : fc1_b;
        const int elems = (g == 0) ? B_ * D_ : (g == 1) ? HID_ * D_ : HID_;
        const int nw = elems >> 1;
        const int n = nw < 32 ? nw : 32;
        if (k < n && nw >= 1) {
            u32 v = ((const u32*)buf)[k * (nw / n)];
            if (!word_bf16_sane(v)) atomicAnd(&fl[g], 0);
        }
    }
    __syncthreads();
    const int xbf = fl[0], wbf = fl[1], b1bf = fl[2];

    const int xoff = b * D_ + seg * 64;
    const int woff = h * D_ + seg * 64;
    float p = 0.f;
    if (!xbf && !wbf) {
        float4 xr[16], wr[16];                      // 16 x float4 = 64 floats
        const float4* xp = (const float4*)((const float*)x + xoff);
        const float4* wp = (const float4*)((const float*)fc1_w + woff);
#pragma unroll
        for (int c = 0; c < 16; ++c) xr[c] = xp[c];
#pragma unroll
        for (int c = 0; c < 16; ++c) wr[c] = wp[c];
#pragma unroll
        for (int c = 0; c < 16; ++c)
            p += xr[c].x * wr[c].x + xr[c].y * wr[c].y + xr[c].z * wr[c].z + xr[c].w * wr[c].w;
    } else if (xbf && wbf) {
        uint4 xr[8], wr[8];                         // 8 x uint4 = 64 bf16
        const uint4* xp = (const uint4*)((const bf16*)x + xoff);
        const uint4* wp = (const uint4*)((const bf16*)fc1_w + woff);
#pragma unroll
        for (int c = 0; c < 8; ++c) xr[c] = xp[c];
#pragma unroll
        for (int c = 0; c < 8; ++c) wr[c] = wp[c];
#pragma unroll
        for (int c = 0; c < 8; ++c) {
            const u32 xw[4] = { xr[c].x, xr[c].y, xr[c].z, xr[c].w };
            const u32 ww[4] = { wr[c].x, wr[c].y, wr[c].z, wr[c].w };
#pragma unroll
            for (int q2 = 0; q2 < 4; ++q2)
                p += bu2f((u16)(xw[q2] & 0xFFFF)) * bu2f((u16)(ww[q2] & 0xFFFF))
                   + bu2f((u16)(xw[q2] >> 16))    * bu2f((u16)(ww[q2] >> 16));
        }
    } else {
        for (int c = 0; c < 64; ++c) p += ldf(x, xoff + c, xbf) * ldf(fc1_w, woff + c, wbf);
    }
    p += __shfl_xor(p, 1);
    p += __shfl_xor(p, 2);
    p += __shfl_xor(p, 4);
    if (seg == 0) {
        p += ldf(fc1_b, h, b1bf);
        ws_hs[b * HID_ + h] = p > 0.f ? p : 0.f;
    }
}

// ---------------------------------------------------------------------------
// Kernel 2: fc2 + softmax + attn outputs + aggregated bias.  grid = 32.
// ---------------------------------------------------------------------------
__global__ __launch_bounds__(256) void fc2_kernel(
    const void* __restrict__ fc2_w,  // [8,256]
    const void* __restrict__ fc2_b,  // [8]
    const void* __restrict__ bias_p, // [8,64]
    const void* __restrict__ xin,    // output-dtype proxy
    const float* __restrict__ ws_hs, // [32,256]
    float* __restrict__ ws_attn, float* __restrict__ ws_aggb,
    void* __restrict__ d_out)
{
    __shared__ float hs[HID_];
    __shared__ float at[NF_];
    __shared__ int fl[4];
    const int b = blockIdx.x, t = threadIdx.x;
    if (t < 4) fl[t] = 1;
    hs[t] = ws_hs[b * HID_ + t];
    __syncthreads();
    if (t < 128) {
        const int g = t >> 5, k = t & 31;
        const void* buf = (g == 0) ? fc2_w : (g == 1) ? fc2_b : (g == 2) ? bias_p : xin;
        const int elems = (g == 0) ? NF_ * HID_ : (g == 1) ? NF_ : (g == 2) ? NF_ * COUT_
                                                : B_ * CIN_ * HW_ * HW_;
        const int nw = elems >> 1;
        const int n = nw < 32 ? nw : 32;
        if (k < n && nw >= 1) {
            u32 v = ((const u32*)buf)[k * (nw / n)];
            if (!word_bf16_sane(v)) atomicAnd(&fl[g], 0);
        }
    }
    __syncthreads();
    const int w2bf = fl[0], b2bf = fl[1], bpbf = fl[2], obf = fl[3];

    const int f = t >> 5, j = t & 31;
    const float* hp = hs + j * 8;
    float p;
    if (w2bf) {
        uint4 u = *(const uint4*)((const bf16*)fc2_w + f * HID_ + j * 8);
        p = bu2f((u16)(u.x & 0xFFFF)) * hp[0] + bu2f((u16)(u.x >> 16)) * hp[1]
          + bu2f((u16)(u.y & 0xFFFF)) * hp[2] + bu2f((u16)(u.y >> 16)) * hp[3]
          + bu2f((u16)(u.z & 0xFFFF)) * hp[4] + bu2f((u16)(u.z >> 16)) * hp[5]
          + bu2f((u16)(u.w & 0xFFFF)) * hp[6] + bu2f((u16)(u.w >> 16)) * hp[7];
    } else {
        const float* r = (const float*)fc2_w + f * HID_ + j * 8;
        float4 a = *(const float4*)r, c = *(const float4*)(r + 4);
        p = a.x * hp[0] + a.y * hp[1] + a.z * hp[2] + a.w * hp[3]
          + c.x * hp[4] + c.y * hp[5] + c.z * hp[6] + c.w * hp[7];
    }
#pragma unroll
    for (int m = 16; m; m >>= 1) p += __shfl_xor(p, m);
    if (j == 0) at[f] = (p + ldf(fc2_b, f, b2bf)) * (1.0f / 30.0f);
    __syncthreads();

    if (t == 0) {
        float m = at[0];
#pragma unroll
        for (int ff = 1; ff < NF_; ++ff) m = fmaxf(m, at[ff]);
        float e[NF_], ssum = 0.f;
#pragma unroll
        for (int ff = 0; ff < NF_; ++ff) { e[ff] = __expf(at[ff] - m); ssum += e[ff]; }
        float inv = 1.0f / ssum;
#pragma unroll
        for (int ff = 0; ff < NF_; ++ff) at[ff] = e[ff] * inv;
    }
    __syncthreads();
    if (t < NF_) {
        ws_attn[b * NF_ + t] = at[t];
        if (obf) ((bf16*)d_out)[CONV_OUT_ELEMS + b * NF_ + t] = f2b(at[t]);
        else    ((float*)d_out)[CONV_OUT_ELEMS + b * NF_ + t] = at[t];
    }
    if (t < COUT_) {
        float s = 0.f;
#pragma unroll
        for (int ff = 0; ff < NF_; ++ff) s += at[ff] * ldf(bias_p, ff * COUT_ + t, bpbf);
        ws_aggb[b * COUT_ + t] = s;
    }
}

// ---------------------------------------------------------------------------
// Kernel 3: aggregate kernel bank -> bf16 in MFMA layout [b][tap][o][ci].
// grid = 32 samples * 16 o-quads = 512 blocks, 256 threads.
// ---------------------------------------------------------------------------
__global__ __launch_bounds__(256) void agg_kernel(
    const void* __restrict__ weight,   // [8][64][64][3][3]
    const float* __restrict__ ws_attn, // [32][8]
    u16* __restrict__ aggw)            // [32][9][64][64] bf16
{
    __shared__ float lds[2304];        // [o_l(4)][ci(64)][tap(9)]
    __shared__ float s_at[NF_];
    __shared__ int   s_wbf;
    const int t  = threadIdx.x;
    const int b  = blockIdx.x >> 4;
    const int o0 = (blockIdx.x & 15) * 4;

    if (t == 0) s_wbf = 1;
    if (t < NF_) s_at[t] = ws_attn[b * NF_ + t];
    __syncthreads();
    if (t < 32) {
        const int nw = WBANK_ >> 1, step = nw / 32;
        u32 v = ((const u32*)weight)[t * step];
        if (!word_bf16_sane(v)) atomicAnd(&s_wbf, 0);
    }
    __syncthreads();
    const int wbf = s_wbf;

#pragma unroll
    for (int j = 0; j < 9; ++j) {
        const int flat = t + 256 * j;              // < 2304
        const int o_l = flat / 576, rr = flat - o_l * 576;  // rr = ci*9+tap
        const int gbase = (o0 + o_l) * 576 + rr;
        float s = 0.f;
        if (wbf) {
#pragma unroll
            for (int f = 0; f < NF_; ++f) s += s_at[f] * b2f(((const bf16*)weight)[f * 36864 + gbase]);
        } else {
#pragma unroll
            for (int f = 0; f < NF_; ++f) s += s_at[f] * ((const float*)weight)[f * 36864 + gbase];
        }
        lds[flat] = s;
    }
    __syncthreads();
#pragma unroll
    for (int j = 0; j < 9; ++j) {
        const int e = t + 256 * j;                 // tap(9) x o_l(4) x ci(64)
        const int tap = e >> 8, o_l = (e >> 6) & 3, ci = e & 63;
        aggw[b * 36864 + tap * 4096 + (o0 + o_l) * 64 + ci] = f2bu(lds[o_l * 576 + ci * 9 + tap]);
    }
}

// ---------------------------------------------------------------------------
// Kernel 4: MFMA conv, LDS-staged B (cheap uint4 copies from NHWC bf16 xin_t),
// direct-global A.  Block = (sample, 4-row chunk); wave wv = 1 output row.
// in_s layout: [r(6)][col(66)][ci(72 pad)] u16; halos zeroed in LDS ->
// K-loop has NO barriers, NO converts, NO per-lane predicates.
// ---------------------------------------------------------------------------
__global__ __launch_bounds__(256) void conv_mfma3(
    const u16*  __restrict__ xin_t,   // [32][64][64][64] NHWC bf16
    const u16*  __restrict__ aggw,    // [32][9][64][64] bf16
    const float* __restrict__ aggb,   // [32][64]
    const void* __restrict__ xin,     // out-dtype proxy
    void* __restrict__ out)
{
    __shared__ __align__(16) u16 smem[28512];   // 57024 B: in_s; reused as out_s
    __shared__ float bias_s[COUT_];
    __shared__ int s_ok;

    const int t    = threadIdx.x;
    const int bz   = blockIdx.x;
    const int b    = bz >> 4;
    const int y0   = (bz & 15) * 4;
    const int wv   = t >> 6;
    const int lane = t & 63, l15 = lane & 15, q = lane >> 4;

    if (t == 0) s_ok = 1;
    __syncthreads();
    if (t < 32) {
        u32 w = ((const u32*)xin)[t * 131072];
        if (!word_bf16_sane(w)) atomicAnd(&s_ok, 0);
    }
    if (t < COUT_) bias_s[t] = aggb[b * COUT_ + t];

    // ---- stage input tile: rows y0-1..y0+4, 64 cols, 64 ci (zero OOB rows)
#pragma unroll
    for (int j = 0; j < 12; ++j) {
        const int item = t + 256 * j;              // 3072 items
        const int cg = item & 7, colm = (item >> 3) & 63, r = item >> 9;
        const int gy = y0 - 1 + r;
        uint4 v = make_uint4(0, 0, 0, 0);
        if (gy >= 0 && gy < HW_)
            v = *(const uint4*)(xin_t + (((b * HW_ + gy) * HW_ + colm) * CIN_ + cg * 8));
        *(uint4*)&smem[(r * 66 + colm + 1) * 72 + cg * 8] = v;
    }
    // zero halo columns (col 0 and 65)
    if (t < 96) {
        const int cg = t & 7, c = (t >> 3) & 1, r = t >> 4;
        *(uint4*)&smem[(r * 66 + c * 65) * 72 + cg * 8] = make_uint4(0, 0, 0, 0);
    }
    __syncthreads();
    const int outbf = s_ok;

    floatx4 acc[4][4];
#pragma unroll
    for (int mt = 0; mt < 4; ++mt)
#pragma unroll
        for (int nt = 0; nt < 4; ++nt) acc[mt][nt] = (floatx4)0.f;

    const u16* Abase = aggw + b * 36864;           // [tap][o][ci]
    const int laneA = l15 * 64 + q * 8;

#pragma unroll
    for (int kh = 0; kh < 3; ++kh) {
        const int gy = y0 + wv + kh - 1;
        if (gy >= 0 && gy < HW_) {                 // wave-uniform skip
#pragma unroll
            for (int kw = 0; kw < 3; ++kw) {
                const u16* Atap = Abase + (kh * 3 + kw) * 4096;
#pragma unroll
                for (int ks = 0; ks < 2; ++ks) {
                    short8 af[4], bf[4];
#pragma unroll
                    for (int mt = 0; mt < 4; ++mt)
                        af[mt] = *(const short8*)(Atap + mt * 1024 + ks * 32 + laneA);
#pragma unroll
                    for (int nt = 0; nt < 4; ++nt)
                        bf[nt] = *(const short8*)&smem[((wv + kh) * 66 + nt * 16 + l15 + kw) * 72
                                                       + ks * 32 + q * 8];
#pragma unroll
                    for (int mt = 0; mt < 4; ++mt)
#pragma unroll
                        for (int nt = 0; nt < 4; ++nt)
                            acc[mt][nt] = __builtin_amdgcn_mfma_f32_16x16x32_bf16(
                                af[mt], bf[nt], acc[mt][nt], 0, 0, 0);
                }
            }
        }
    }

    __syncthreads();   // all LDS reads done; reuse smem as out staging
    u16* out_s = smem; // [wv][o][68]
#pragma unroll
    for (int mt = 0; mt < 4; ++mt) {
        floatx4 bb = *(const floatx4*)&bias_s[mt * 16 + q * 4];
#pragma unroll
        for (int nt = 0; nt < 4; ++nt) {
#pragma unroll
            for (int rg = 0; rg < 4; ++rg) {
                const float v = acc[mt][nt][rg] + bb[rg];
                out_s[(wv * 64 + (mt * 16 + q * 4 + rg)) * 68 + nt * 16 + l15] = f2bu(v);
            }
        }
    }
    __syncthreads();
#pragma unroll
    for (int j = 0; j < 16; ++j) {
        const int c = t + 256 * j;                 // 4096 chunks of 4 elems
        const int x0 = (c & 15) * 4, o = (c >> 4) & 63, w2 = c >> 10;
        const u16* src = &out_s[(w2 * 64 + o) * 68 + x0];
        const u16 h0 = src[0], h1 = src[1], h2 = src[2], h3 = src[3];
        const int gidx = ((b * COUT_ + o) * HW_ + (y0 + w2)) * HW_ + x0;
        if (outbf) {
            uint2 pk; pk.x = (u32)h0 | ((u32)h1 << 16); pk.y = (u32)h2 | ((u32)h3 << 16);
            *(uint2*)((u16*)out + gidx) = pk;
        } else {
            float4 f; f.x = bu2f(h0); f.y = bu2f(h1); f.z = bu2f(h2); f.w = bu2f(h3);
            *(float4*)((float*)out + gidx) = f;
        }
    }
}

// ---------------------------------------------------------------------------
extern "C" void kernel_launch(void* const* d_in, const int* in_sizes, int n_in,
                              void* d_out, int out_size, void* d_ws, size_t ws_size,
                              hipStream_t stream) {
    const void* x      = d_in[0];
    const void* xin    = d_in[1];
    const void* fc1_w  = d_in[2];
    const void* fc1_b  = d_in[3];
    const void* fc2_w  = d_in[4];
    const void* fc2_b  = d_in[5];
    const void* weight = d_in[6];
    const void* bias_p = d_in[7];

    float* ws      = (float*)d_ws;
    float* ws_attn = ws;                    // 256 floats
    float* ws_aggb = ws + 256;              // 2048 floats
    float* ws_hs   = ws + 2304;             // 8192 floats [32][256]
    u16*   ws_aggw = (u16*)(ws + 10496);    // 1,179,648 u16 (=589,824 float slots)
    u16*   ws_xint = (u16*)(ws + 600320);   // 8,388,608 u16 = 16.8 MB

    prep_kernel<<<dim3(2048 + HID_), dim3(256), 0, stream>>>(
        xin, x, fc1_w, fc1_b, ws_xint, ws_hs);

    fc2_kernel<<<dim3(B_), dim3(256), 0, stream>>>(
        fc2_w, fc2_b, bias_p, xin, ws_hs, ws_attn, ws_aggb, d_out);

    agg_kernel<<<dim3(B_ * 16), dim3(256), 0, stream>>>(weight, ws_attn, ws_aggw);

    conv_mfma3<<<dim3(B_ * 16), dim3(256), 0, stream>>>(
        ws_xint, ws_aggw, ws_aggb, xin, d_out);
}

// Round 9
// 138.762 us; speedup vs baseline: 1.1329x; 1.0610x over previous
//
#include <hip/hip_runtime.h>
#include <hip/hip_bf16.h>

typedef __hip_bfloat16 bf16;
typedef unsigned short u16;
typedef unsigned int   u32;

#define B_    32
#define D_    512
#define HID_  256
#define NF_   8
#define CIN_  64
#define COUT_ 64
#define HW_   64
#define CONV_OUT_ELEMS (B_ * COUT_ * HW_ * HW_)   // 8388608
#define WBANK_ (NF_ * 36864)                       // weight elems

typedef __attribute__((ext_vector_type(8))) short  short8;   // 8 bf16 = 4 VGPRs (MFMA A/B frag)
typedef __attribute__((ext_vector_type(4))) float  floatx4;  // MFMA C/D frag

__device__ inline float b2f(bf16 v) { return __bfloat162float(v); }
__device__ inline bf16  f2b(float f) { return __float2bfloat16(f); }
__device__ inline u16 f2bu(float f) { union { bf16 h; u16 u; } c; c.h = __float2bfloat16(f); return c.u; }
__device__ inline float bu2f(u16 u) { union { u32 i; float f; } c; c.i = ((u32)u) << 16; return c.f; }

__device__ inline float ldf(const void* p, int i, int isbf) {
    return isbf ? __bfloat162float(((const bf16*)p)[i]) : ((const float*)p)[i];
}

// word is "bf16-sane" if low 16 bits decode to zero or normal-exponent bf16
__device__ inline int word_bf16_sane(u32 v) {
    u32 lo = v & 0xFFFFu;
    u32 ex = (lo >> 7) & 0xFFu;
    return (lo == 0u || (ex >= 64u && ex <= 191u)) ? 1 : 0;
}

// ---------------------------------------------------------------------------
// Kernel 1: prep = xin transpose (blocks 0..2047) + fc1 (blocks 2048..2303).
// Transpose: NCHW (fp32 or bf16) -> NHWC bf16 xin_t[b][y][x][ci].
// ---------------------------------------------------------------------------
__global__ __launch_bounds__(256) void prep_kernel(
    const void* __restrict__ xin,    // [32][64][64][64] NCHW
    const void* __restrict__ x,      // [32,512]
    const void* __restrict__ fc1_w,  // [256,512]
    const void* __restrict__ fc1_b,  // [256]
    u16* __restrict__ xin_t,         // [32][64][64][64] NHWC bf16
    float* __restrict__ ws_hs)       // [32,256]
{
    __shared__ u16 tr[64][66];
    __shared__ int fl[4];
    const int blk = blockIdx.x;
    const int t = threadIdx.x;

    if (blk < 2048) {
        // ---------------- transpose one (b, y) row ----------------
        const int b = blk >> 6, y = blk & 63;
        if (t == 0) fl[0] = 1;
        __syncthreads();
        if (t < 32) {
            u32 w = ((const u32*)xin)[t * 131072];
            if (!word_bf16_sane(w)) atomicAnd(&fl[0], 0);
        }
        __syncthreads();
        const int inbf = fl[0];

        const int ci = t >> 2, xq = (t & 3) * 16;
        u16 vals[16];
        if (inbf) {
            const bf16* src = (const bf16*)xin + (((b * CIN_ + ci) * HW_ + y) * HW_ + xq);
            uint4 v0 = *(const uint4*)src;
            uint4 v1 = *(const uint4*)(src + 8);
            const u32 w8[8] = { v0.x, v0.y, v0.z, v0.w, v1.x, v1.y, v1.z, v1.w };
#pragma unroll
            for (int k = 0; k < 8; ++k) {
                vals[2 * k]     = (u16)(w8[k] & 0xFFFF);
                vals[2 * k + 1] = (u16)(w8[k] >> 16);
            }
        } else {
            const float* src = (const float*)xin + (((b * CIN_ + ci) * HW_ + y) * HW_ + xq);
#pragma unroll
            for (int c = 0; c < 4; ++c) {
                float4 f = *(const float4*)(src + c * 4);
                vals[c * 4 + 0] = f2bu(f.x); vals[c * 4 + 1] = f2bu(f.y);
                vals[c * 4 + 2] = f2bu(f.z); vals[c * 4 + 3] = f2bu(f.w);
            }
        }
#pragma unroll
        for (int k = 0; k < 16; ++k) tr[xq + k][ci] = vals[k];
        __syncthreads();

        const int px = t >> 2, cg = (t & 3) * 16;
        u32 wd[8];
#pragma unroll
        for (int w = 0; w < 8; ++w)
            wd[w] = (u32)tr[px][cg + 2 * w] | ((u32)tr[px][cg + 2 * w + 1] << 16);
        u16* dst = xin_t + (((b * HW_ + y) * HW_ + px) * CIN_ + cg);
        ((uint4*)dst)[0] = make_uint4(wd[0], wd[1], wd[2], wd[3]);
        ((uint4*)dst)[1] = make_uint4(wd[4], wd[5], wd[6], wd[7]);
        return;
    }

    // ---------------- fc1: hidden unit h ----------------
    const int h = blk - 2048;
    const int b = t >> 3, seg = t & 7;
    if (t < 3) fl[t] = 1;
    __syncthreads();
    if (t < 96) {
        const int g = t >> 5, k = t & 31;
        const void* buf = (g == 0) ? x : (g == 1) ? fc1_w : fc1_b;
        const int elems = (g == 0) ? B_ * D_ : (g == 1) ? HID_ * D_ : HID_;
        const int nw = elems >> 1;
        const int n = nw < 32 ? nw : 32;
        if (k < n && nw >= 1) {
            u32 v = ((const u32*)buf)[k * (nw / n)];
            if (!word_bf16_sane(v)) atomicAnd(&fl[g], 0);
        }
    }
    __syncthreads();
    const int xbf = fl[0], wbf = fl[1], b1bf = fl[2];

    const int xoff = b * D_ + seg * 64;
    const int woff = h * D_ + seg * 64;
    float p = 0.f;
    if (!xbf && !wbf) {
        float4 xr[16], wr[16];                      // 16 x float4 = 64 floats
        const float4* xp = (const float4*)((const float*)x + xoff);
        const float4* wp = (const float4*)((const float*)fc1_w + woff);
#pragma unroll
        for (int c = 0; c < 16; ++c) xr[c] = xp[c];
#pragma unroll
        for (int c = 0; c < 16; ++c) wr[c] = wp[c];
#pragma unroll
        for (int c = 0; c < 16; ++c)
            p += xr[c].x * wr[c].x + xr[c].y * wr[c].y + xr[c].z * wr[c].z + xr[c].w * wr[c].w;
    } else if (xbf && wbf) {
        uint4 xr[8], wr[8];                         // 8 x uint4 = 64 bf16
        const uint4* xp = (const uint4*)((const bf16*)x + xoff);
        const uint4* wp = (const uint4*)((const bf16*)fc1_w + woff);
#pragma unroll
        for (int c = 0; c < 8; ++c) xr[c] = xp[c];
#pragma unroll
        for (int c = 0; c < 8; ++c) wr[c] = wp[c];
#pragma unroll
        for (int c = 0; c < 8; ++c) {
            const u32 xw[4] = { xr[c].x, xr[c].y, xr[c].z, xr[c].w };
            const u32 ww[4] = { wr[c].x, wr[c].y, wr[c].z, wr[c].w };
#pragma unroll
            for (int q2 = 0; q2 < 4; ++q2)
                p += bu2f((u16)(xw[q2] & 0xFFFF)) * bu2f((u16)(ww[q2] & 0xFFFF))
                   + bu2f((u16)(xw[q2] >> 16))    * bu2f((u16)(ww[q2] >> 16));
        }
    } else {
        for (int c = 0; c < 64; ++c) p += ldf(x, xoff + c, xbf) * ldf(fc1_w, woff + c, wbf);
    }
    p += __shfl_xor(p, 1);
    p += __shfl_xor(p, 2);
    p += __shfl_xor(p, 4);
    if (seg == 0) {
        p += ldf(fc1_b, h, b1bf);
        ws_hs[b * HID_ + h] = p > 0.f ? p : 0.f;
    }
}

// ---------------------------------------------------------------------------
// Kernel 2: agg2 = fc2+softmax (recomputed per block, L2-hot) + bias agg +
// weight bank aggregation -> bf16 MFMA layout [b][tap][o][ci].
// grid = 32 samples * 16 o-quads = 512 blocks, 256 threads.
// ---------------------------------------------------------------------------
__global__ __launch_bounds__(256) void agg2_kernel(
    const void* __restrict__ weight,   // [8][64][64][3][3]
    const void* __restrict__ fc2_w,    // [8,256]
    const void* __restrict__ fc2_b,    // [8]
    const void* __restrict__ bias_p,   // [8,64]
    const void* __restrict__ xin,      // out-dtype proxy
    const float* __restrict__ ws_hs,   // [32,256]
    float* __restrict__ ws_aggb,       // [32,64]
    u16* __restrict__ aggw,            // [32][9][64][64] bf16
    void* __restrict__ d_out)
{
    __shared__ float lds[2304];        // [o_l(4)][ci(64)][tap(9)]
    __shared__ float hs[HID_];
    __shared__ float at[NF_];
    __shared__ int   fl[5];
    const int t  = threadIdx.x;
    const int b  = blockIdx.x >> 4;
    const int o0 = (blockIdx.x & 15) * 4;

    if (t < 5) fl[t] = 1;
    hs[t] = ws_hs[b * HID_ + t];
    __syncthreads();
    if (t < 160) {
        const int g = t >> 5, k = t & 31;
        const void* buf = (g == 0) ? fc2_w : (g == 1) ? fc2_b : (g == 2) ? bias_p
                        : (g == 3) ? xin : weight;
        const int elems = (g == 0) ? NF_ * HID_ : (g == 1) ? NF_ : (g == 2) ? NF_ * COUT_
                        : (g == 3) ? B_ * CIN_ * HW_ * HW_ : WBANK_;
        const int nw = elems >> 1;
        const int n = nw < 32 ? nw : 32;
        if (k < n && nw >= 1) {
            u32 v = ((const u32*)buf)[k * (nw / n)];
            if (!word_bf16_sane(v)) atomicAnd(&fl[g], 0);
        }
    }
    __syncthreads();
    const int w2bf = fl[0], b2bf = fl[1], bpbf = fl[2], obf = fl[3], wbf = fl[4];

    // logits: f = t>>5 (8 groups x 32 lanes), lane j covers k = j*8..j*8+8
    {
        const int f = t >> 5, j = t & 31;
        const float* hp = hs + j * 8;
        float p;
        if (w2bf) {
            uint4 u = *(const uint4*)((const bf16*)fc2_w + f * HID_ + j * 8);
            p = bu2f((u16)(u.x & 0xFFFF)) * hp[0] + bu2f((u16)(u.x >> 16)) * hp[1]
              + bu2f((u16)(u.y & 0xFFFF)) * hp[2] + bu2f((u16)(u.y >> 16)) * hp[3]
              + bu2f((u16)(u.z & 0xFFFF)) * hp[4] + bu2f((u16)(u.z >> 16)) * hp[5]
              + bu2f((u16)(u.w & 0xFFFF)) * hp[6] + bu2f((u16)(u.w >> 16)) * hp[7];
        } else {
            const float* r = (const float*)fc2_w + f * HID_ + j * 8;
            float4 a = *(const float4*)r, c = *(const float4*)(r + 4);
            p = a.x * hp[0] + a.y * hp[1] + a.z * hp[2] + a.w * hp[3]
              + c.x * hp[4] + c.y * hp[5] + c.z * hp[6] + c.w * hp[7];
        }
#pragma unroll
        for (int m = 16; m; m >>= 1) p += __shfl_xor(p, m);
        if (j == 0) at[f] = (p + ldf(fc2_b, f, b2bf)) * (1.0f / 30.0f);
    }
    __syncthreads();
    if (t == 0) {
        float m = at[0];
#pragma unroll
        for (int ff = 1; ff < NF_; ++ff) m = fmaxf(m, at[ff]);
        float e[NF_], ssum = 0.f;
#pragma unroll
        for (int ff = 0; ff < NF_; ++ff) { e[ff] = __expf(at[ff] - m); ssum += e[ff]; }
        float inv = 1.0f / ssum;
#pragma unroll
        for (int ff = 0; ff < NF_; ++ff) at[ff] = e[ff] * inv;
    }
    __syncthreads();

    if ((blockIdx.x & 15) == 0 && t < NF_) {
        if (obf) ((bf16*)d_out)[CONV_OUT_ELEMS + b * NF_ + t] = f2b(at[t]);
        else    ((float*)d_out)[CONV_OUT_ELEMS + b * NF_ + t] = at[t];
    }
    if (t < 4) {
        const int o = o0 + t;
        float s = 0.f;
#pragma unroll
        for (int ff = 0; ff < NF_; ++ff) s += at[ff] * ldf(bias_p, ff * COUT_ + o, bpbf);
        ws_aggb[b * COUT_ + o] = s;
    }

    // ---- weight aggregation for o0..o0+3
#pragma unroll
    for (int j = 0; j < 9; ++j) {
        const int flat = t + 256 * j;              // < 2304
        const int o_l = flat / 576, rr = flat - o_l * 576;  // rr = ci*9+tap
        const int gbase = (o0 + o_l) * 576 + rr;
        float s = 0.f;
        if (wbf) {
#pragma unroll
            for (int f = 0; f < NF_; ++f) s += at[f] * b2f(((const bf16*)weight)[f * 36864 + gbase]);
        } else {
#pragma unroll
            for (int f = 0; f < NF_; ++f) s += at[f] * ((const float*)weight)[f * 36864 + gbase];
        }
        lds[flat] = s;
    }
    __syncthreads();
#pragma unroll
    for (int j = 0; j < 9; ++j) {
        const int e = t + 256 * j;                 // tap(9) x o_l(4) x ci(64)
        const int tap = e >> 8, o_l = (e >> 6) & 3, ci = e & 63;
        aggw[b * 36864 + tap * 4096 + (o0 + o_l) * 64 + ci] = f2bu(lds[o_l * 576 + ci * 9 + tap]);
    }
}

// ---------------------------------------------------------------------------
// Kernel 3: MFMA conv, BOTH operands LDS-staged per ci-phase (32 ci each).
// A_s[tap(9)][o(64)][40pad], B_s[r(6)][col(66)][40pad] (80B strides: 16B-
// aligned uint4 stores, 2-way bank aliasing = free). OOB rows/cols zeroed in
// LDS -> K-loop is 18 straight-line iters of 8 ds_read_b128 + 16 MFMA:
// no global loads, no barriers, no branches.
// ---------------------------------------------------------------------------
__global__ __launch_bounds__(256) void conv_mfma4(
    const u16*  __restrict__ xin_t,   // [32][64][64][64] NHWC bf16
    const u16*  __restrict__ aggw,    // [32][9][64][64] bf16
    const float* __restrict__ aggb,   // [32][64]
    const void* __restrict__ xin,     // out-dtype proxy
    void* __restrict__ out)
{
    __shared__ __align__(16) u16 smem[38880];   // 77760 B: A_s(23040)+B_s(15840); reused as out_s
    __shared__ float bias_s[COUT_];
    __shared__ int s_ok;
    u16* A_s = smem;            // [tap][o][40]
    u16* B_s = smem + 23040;    // [r][col][40]

    const int t    = threadIdx.x;
    const int bz   = blockIdx.x;
    const int b    = bz >> 4;
    const int y0   = (bz & 15) * 4;
    const int wv   = t >> 6;
    const int lane = t & 63, l15 = lane & 15, q = lane >> 4;

    if (t == 0) s_ok = 1;
    __syncthreads();
    if (t < 32) {
        u32 w = ((const u32*)xin)[t * 131072];
        if (!word_bf16_sane(w)) atomicAnd(&s_ok, 0);
    }
    if (t < COUT_) bias_s[t] = aggb[b * COUT_ + t];
    __syncthreads();
    const int outbf = s_ok;

    floatx4 acc[4][4];
#pragma unroll
    for (int mt = 0; mt < 4; ++mt)
#pragma unroll
        for (int nt = 0; nt < 4; ++nt) acc[mt][nt] = (floatx4)0.f;

    const u16* Abase = aggw + b * 36864;           // [tap][o][ci]

    for (int ph = 0; ph < 2; ++ph) {
        const int ci0 = ph * 32;
        // ---- stage A: 9 taps x 64 o x 4 ci-quads = 2304 uint4 items
#pragma unroll
        for (int j = 0; j < 9; ++j) {
            const int item = t + 256 * j;          // exactly 2304
            const int cg = item & 3, o = (item >> 2) & 63, tap = item >> 8;
            uint4 v = *(const uint4*)(Abase + tap * 4096 + o * 64 + ci0 + cg * 8);
            *(uint4*)&A_s[tap * 2560 + o * 40 + cg * 8] = v;
        }
        // ---- stage B: 6 rows x 66 cols x 4 ci-quads = 1584 items (OOB -> 0)
#pragma unroll
        for (int j = 0; j < 7; ++j) {
            const int item = t + 256 * j;
            if (item < 1584) {
                const int cg = item & 3, col = (item >> 2) % 66, r = item / 264;
                const int gy = y0 - 1 + r, gx = col - 1;
                uint4 v = make_uint4(0, 0, 0, 0);
                if (gy >= 0 && gy < HW_ && gx >= 0 && gx < HW_)
                    v = *(const uint4*)(xin_t + (((b * HW_ + gy) * HW_ + gx) * CIN_ + ci0 + cg * 8));
                *(uint4*)&B_s[r * 2640 + col * 40 + cg * 8] = v;
            }
        }
        __syncthreads();
        // ---- K-loop: 9 taps, K=32 per tap (= this phase's full ci range)
#pragma unroll
        for (int tap = 0; tap < 9; ++tap) {
            const int kh = tap / 3, kw = tap % 3;
            short8 af[4], bf[4];
#pragma unroll
            for (int mt = 0; mt < 4; ++mt)
                af[mt] = *(const short8*)&A_s[tap * 2560 + (mt * 16 + l15) * 40 + q * 8];
#pragma unroll
            for (int nt = 0; nt < 4; ++nt)
                bf[nt] = *(const short8*)&B_s[(wv + kh) * 2640 + (nt * 16 + l15 + kw) * 40 + q * 8];
#pragma unroll
            for (int mt = 0; mt < 4; ++mt)
#pragma unroll
                for (int nt = 0; nt < 4; ++nt)
                    acc[mt][nt] = __builtin_amdgcn_mfma_f32_16x16x32_bf16(
                        af[mt], bf[nt], acc[mt][nt], 0, 0, 0);
        }
        __syncthreads();   // protect next phase's (or epilogue's) LDS overwrite
    }

    // epilogue: + bias, stage in LDS for coalesced global write
    u16* out_s = smem; // [wv][o][68]
#pragma unroll
    for (int mt = 0; mt < 4; ++mt) {
        floatx4 bb = *(const floatx4*)&bias_s[mt * 16 + q * 4];
#pragma unroll
        for (int nt = 0; nt < 4; ++nt) {
#pragma unroll
            for (int rg = 0; rg < 4; ++rg) {
                const float v = acc[mt][nt][rg] + bb[rg];
                out_s[(wv * 64 + (mt * 16 + q * 4 + rg)) * 68 + nt * 16 + l15] = f2bu(v);
            }
        }
    }
    __syncthreads();
#pragma unroll
    for (int j = 0; j < 16; ++j) {
        const int c = t + 256 * j;                 // 4096 chunks of 4 elems
        const int x0 = (c & 15) * 4, o = (c >> 4) & 63, w2 = c >> 10;
        const u16* src = &out_s[(w2 * 64 + o) * 68 + x0];
        const u16 h0 = src[0], h1 = src[1], h2 = src[2], h3 = src[3];
        const int gidx = ((b * COUT_ + o) * HW_ + (y0 + w2)) * HW_ + x0;
        if (outbf) {
            uint2 pk; pk.x = (u32)h0 | ((u32)h1 << 16); pk.y = (u32)h2 | ((u32)h3 << 16);
            *(uint2*)((u16*)out + gidx) = pk;
        } else {
            float4 f; f.x = bu2f(h0); f.y = bu2f(h1); f.z = bu2f(h2); f.w = bu2f(h3);
            *(float4*)((float*)out + gidx) = f;
        }
    }
}

// ---------------------------------------------------------------------------
extern "C" void kernel_launch(void* const* d_in, const int* in_sizes, int n_in,
                              void* d_out, int out_size, void* d_ws, size_t ws_size,
                              hipStream_t stream) {
    const void* x      = d_in[0];
    const void* xin    = d_in[1];
    const void* fc1_w  = d_in[2];
    const void* fc1_b  = d_in[3];
    const void* fc2_w  = d_in[4];
    const void* fc2_b  = d_in[5];
    const void* weight = d_in[6];
    const void* bias_p = d_in[7];

    float* ws      = (float*)d_ws;
    float* ws_aggb = ws + 256;              // 2048 floats
    float* ws_hs   = ws + 2304;             // 8192 floats [32][256]
    u16*   ws_aggw = (u16*)(ws + 10496);    // 1,179,648 u16
    u16*   ws_xint = (u16*)(ws + 600320);   // 8,388,608 u16 = 16.8 MB

    prep_kernel<<<dim3(2048 + HID_), dim3(256), 0, stream>>>(
        xin, x, fc1_w, fc1_b, ws_xint, ws_hs);

    agg2_kernel<<<dim3(B_ * 16), dim3(256), 0, stream>>>(
        weight, fc2_w, fc2_b, bias_p, xin, ws_hs, ws_aggb, ws_aggw, d_out);

    conv_mfma4<<<dim3(B_ * 16), dim3(256), 0, stream>>>(
        ws_xint, ws_aggw, ws_aggb, xin, d_out);
}